// Round 10
// baseline (139.218 us; speedup 1.0000x reference)
//
#include <hip/hip_runtime.h>
#include <stdint.h>

// ModulatedConv2D: B=8, IC=OC=512, K=3, H=W=32
// 3 dispatches: style (sm, sm2), prep (Wtf repack + dpart demod partials +
// xsp repack), conv (implicit GEMM, 32x32x16 f16 MFMA).
//
// R10 change: R9 (X direct global->VGPR) had a counted-vmcnt ordering bug:
// prefetch issued LOADX before stageA, so the steady-state oldest-3 at
// vmcnt(27) were X register loads, NOT A's global_load_lds -> barrier let
// ds_read race the in-flight LDS writes. Fix: issue stageA(st+1) BEFORE
// LOADX(st+1); queue = [A(st)3, X(st)12, A(st+1)3, X(st+1)12], vmcnt(27)
// drains exactly A(st); X registers are guarded by compiler-inserted
// waits at first MFMA use. Theory under test unchanged (m169: drop
// barrier-coupled staging of L3-resident X with no block-level reuse).

#define B_   8
#define IC_  512
#define OC_  512

static constexpr float RC_DENSE = 0.04419417382415922f;   // 1/sqrt(512)
static constexpr float RC_CONV  = 0.014731391274719739f;  // 1/sqrt(4608)

typedef _Float16 half8    __attribute__((ext_vector_type(8)));
typedef float    floatx16 __attribute__((ext_vector_type(16)));

// async global->LDS, 16B per lane; LDS dest = wave-uniform base + lane*16
__device__ __forceinline__ void g2l(const void* g, void* l) {
  __builtin_amdgcn_global_load_lds(
      (const __attribute__((address_space(1))) void*)g,
      (__attribute__((address_space(3))) void*)l, 16, 0, 0);
}

// ---- sm = (w@(RC_DENSE*dw) + db + 1)*RC_CONV ; sm2 = sm^2 ----
__global__ __launch_bounds__(256) void style_kernel(
    const float* __restrict__ wv, const float* __restrict__ dw,
    const float* __restrict__ db, float* __restrict__ sm,
    float* __restrict__ sm2) {
  const int b = blockIdx.y;
  const int i = blockIdx.x * 64 + (threadIdx.x & 63);
  const int jg = threadIdx.x >> 6;
  __shared__ float red[4][64];
  float p = 0.f;
  for (int j = jg * 128; j < jg * 128 + 128; ++j)
    p += wv[b * IC_ + j] * dw[(size_t)j * IC_ + i];
  red[jg][threadIdx.x & 63] = p;
  __syncthreads();
  if (threadIdx.x < 64) {
    float s = red[0][threadIdx.x] + red[1][threadIdx.x] +
              red[2][threadIdx.x] + red[3][threadIdx.x];
    s = s * RC_DENSE + db[i] + 1.0f;
    float v = s * RC_CONV;
    sm[b * IC_ + i] = v;
    sm2[b * IC_ + i] = v * v;
  }
}

// ---------------- prep: 512 blocks (2/CU) ----------------
// bid<256 (wts role): 32oc x 32ic half-tile; Wtf[by][icb][ktq 36][oc64][8] f16
//   + dpart[icb][b][oc] = sum_icl sm2 * sum_t cw^2 (disjoint oc, no atomics)
// bid>=256 (xsp role): per (b,h) row; xsp[b][icb][r34][kk2][kq2][C34][8] f16
__global__ __launch_bounds__(256) void prep_kernel(
    const float* __restrict__ cw, const float* __restrict__ x,
    const float* __restrict__ sm, const float* __restrict__ sm2,
    _Float16* __restrict__ Wtf, float* __restrict__ dpart,
    _Float16* __restrict__ xsp) {
  __shared__ __align__(16) char smem[33280];
  const int bid = blockIdx.x;
  const int tid = threadIdx.x;
  if (bid < 256) {
    // ---------------- wts + dpart role ----------------
    _Float16* LA = (_Float16*)smem;                // 18432 B
    float* redall = (float*)(smem + 18432);        // 8192 B (8b x 8g x 32oc)
    const int by2 = bid >> 4, icb = bid & 15;
    const int by = by2 >> 1, h2 = by2 & 1;
    const int oc0 = by * 64 + h2 * 32, ic0 = icb * 32;
    const int ocl = tid & 31, g = tid >> 5;        // g 0..7
    float sq4[4] = {};
    for (int m = 0; m < 36; ++m) {
      int r = m * 8 + g;                 // r = t*32+icl; t=m>>2, icl=8*(m&3)+g
      int t = r >> 5, icl = r & 31;
      float v = cw[(size_t)(t * IC_ + ic0 + icl) * OC_ + oc0 + ocl];  // 128B seg
      sq4[m & 3] += v * v;
      LA[m * 256 + ocl * 8 + g] = (_Float16)v;     // ktq == m, j == g
    }
    for (int b = 0; b < 8; ++b) {
      float p = 0.f;
      for (int s = 0; s < 4; ++s)
        p += sm2[b * IC_ + ic0 + g + 8 * s] * sq4[s];
      redall[(b * 8 + g) * 32 + ocl] = p;
    }
    __syncthreads();
    // Wtf: 1152 contiguous-per-wave b128 chunks
    _Float16* dst = Wtf + (size_t)(by * 16 + icb) * 18432;
    for (int it = 0; it < 5; ++it) {
      int c = it * 256 + tid;
      if (c < 1152) {
        int m = c >> 5, o2 = c & 31;
        *(half8*)(dst + (size_t)(m * 64 + h2 * 32 + o2) * 8) =
            *(const half8*)&LA[m * 256 + o2 * 8];
      }
    }
    // dpart: reduce over g
    const int bb = tid >> 5, o3 = tid & 31;
    float s = 0.f;
    for (int g2 = 0; g2 < 8; ++g2) s += redall[(bb * 8 + g2) * 32 + o3];
    dpart[(size_t)icb * 4096 + bb * OC_ + oc0 + o3] = s;
  } else {
    // ---------------- xsp role ----------------
    _Float16* Xt = (_Float16*)smem;                // 32*520*2 = 33280 B
    const int rb = bid - 256;
    const int b = rb >> 5, h = rb & 31;
    for (int k = 0; k < 16; ++k) {
      int idx = k * 256 + tid;           // 512 ic * 8 w-quads
      int ic = idx >> 3, wc = (idx & 7) * 4;
      float4 v = *(const float4*)&x[((size_t)(b * IC_ + ic) * 32 + h) * 32 + wc];
      float s = sm[b * IC_ + ic];
      Xt[(wc + 0) * 520 + ic] = (_Float16)(v.x * s);
      Xt[(wc + 1) * 520 + ic] = (_Float16)(v.y * s);
      Xt[(wc + 2) * 520 + ic] = (_Float16)(v.z * s);
      Xt[(wc + 3) * 520 + ic] = (_Float16)(v.w * s);
    }
    __syncthreads();
    _Float16* xb = xsp + (size_t)b * 16 * 36992;
    const int r = h + 1;
    half8 z = {};
    for (int it = 0; it < 9; ++it) {     // 16 icb * 4 kkq * 34 C = 2176 chunks
      int c = it * 256 + tid;
      if (c < 2176) {
        int icb = c / 136, rem = c - 136 * icb, kkq = rem / 34, C = rem - 34 * kkq;
        half8 val = z;
        if (C != 0 && C != 33)
          val = *(const half8*)&Xt[(C - 1) * 520 + icb * 32 + kkq * 8];
        *(half8*)&xb[(size_t)icb * 36992 + (size_t)r * 1088 + kkq * 272 + C * 8] = val;
      }
    }
    if (h == 0 || h == 31) {             // zero top/bottom padded rows
      const int rz = (h == 0) ? 0 : 33;
      for (int it = 0; it < 9; ++it) {
        int c = it * 256 + tid;
        if (c < 2176) {
          int icb = c / 136, rem = c - 136 * icb, kkq = rem / 34, C = rem - 34 * kkq;
          *(half8*)&xb[(size_t)icb * 36992 + (size_t)rz * 1088 + kkq * 272 + C * 8] = z;
        }
      }
    }
  }
}

// ---- conv: block 32oc x 256px (8 rows), grid (x 16, bx 4, b 8) = 512 ----
// blockIdx.x = byq + 8*hoc; XCD = linear%8 = byq (weight slice locality).
// 4 waves/block, wave w owns output rows h0+2w, h0+2w+1 (acc[2]x16).
// Per sub-step (icb x kk, 32 total): A-quarter (9216 B) LDS-staged
// (double-buffered, uniform 3 g2l/wave = 12 groups x 48 lanes); X read
// DIRECTLY global->VGPR (12 dwordx4, offsets fold into one base),
// pipelined one iteration ahead (xvA/xvB).
// Issue order per step: stageA(st+1) FIRST, then LOADX(st+1) -> queue
// [A(st)3, X(st)12, A(st+1)3, X(st+1)12]; vmcnt(27) drains exactly A(st)
// before the barrier (the only cross-wave guarantee needed); X(st)
// registers are guarded by compiler-inserted waits at first MFMA use.

#define LOADX(XV, ST)                                                        \
  {                                                                          \
    const _Float16* xb_ =                                                    \
        gXw + (size_t)((ST) >> 1) * 36992 + ((ST) & 1) * 544;                \
    _Pragma("unroll")                                                        \
    for (int s_ = 0; s_ < 4; ++s_)                                           \
      _Pragma("unroll")                                                      \
      for (int kw_ = 0; kw_ < 3; ++kw_)                                      \
        XV[s_][kw_] = *(const half8*)(xb_ + s_ * 1088 + kw_ * 8);            \
  }

#define COMPUTE(XV, CUR)                                                     \
  {                                                                          \
    const _Float16* Ap = &As[CUR][0] + kq * 256 + n * 8;                     \
    half8 a_[9];                                                             \
    _Pragma("unroll")                                                        \
    for (int t_ = 0; t_ < 9; ++t_) a_[t_] = *(const half8*)(Ap + t_ * 512);  \
    __builtin_amdgcn_s_setprio(1);                                           \
    _Pragma("unroll")                                                        \
    for (int s_ = 0; s_ < 4; ++s_)                                           \
      _Pragma("unroll")                                                      \
      for (int kw_ = 0; kw_ < 3; ++kw_)                                      \
        _Pragma("unroll")                                                    \
        for (int kh_ = 0; kh_ < 3; ++kh_) {                                  \
          int j_ = s_ - kh_;                                                 \
          if (j_ >= 0 && j_ < 2)                                             \
            acc[j_] = __builtin_amdgcn_mfma_f32_32x32x16_f16(                \
                a_[kh_ * 3 + kw_], XV[s_][kw_], acc[j_], 0, 0, 0);           \
        }                                                                    \
    __builtin_amdgcn_s_setprio(0);                                           \
  }

#define STEP(ST, CUR, XVU, XVN)                                              \
  {                                                                          \
    if ((ST) + 1 < 32) {                                                     \
      stageA((ST) + 1, (CUR) ^ 1);      /* A first: oldest at the wait */    \
      LOADX(XVN, (ST) + 1)                                                   \
      __builtin_amdgcn_sched_barrier(0);                                     \
      asm volatile("s_waitcnt vmcnt(27)" ::: "memory");                      \
    } else {                                                                 \
      __builtin_amdgcn_sched_barrier(0);                                     \
      asm volatile("s_waitcnt vmcnt(12)" ::: "memory");                      \
    }                                                                        \
    __builtin_amdgcn_s_barrier();                                            \
    __builtin_amdgcn_sched_barrier(0);                                       \
    COMPUTE(XVU, CUR)                                                        \
    __builtin_amdgcn_sched_barrier(0);                                       \
    __builtin_amdgcn_s_barrier();                                            \
  }

__global__ __launch_bounds__(256, 2) void conv_kernel(
    const _Float16* __restrict__ Wtf,   // [8 byq][16 icb][36 m][64 oc][8]
    const _Float16* __restrict__ xsp,   // [8 b][16 icb][34 r][2 kk][2 kq][34 C][8]
    const float* __restrict__ dpart,    // [16 icb][8 b][512 oc]
    float* __restrict__ out) {          // [8][512][32][32]
  const int byq = blockIdx.x & 7, hoc = blockIdx.x >> 3;
  const int bx = blockIdx.y, b = blockIdx.z;
  const int tid = threadIdx.x, lane = tid & 63, w = tid >> 6;
  const int n = lane & 31, kq = lane >> 5;
  const int h0 = bx * 8;                // output rows h0..h0+7; padded h0..h0+9

  __shared__ __align__(16) _Float16 As[2][4608];   // 9216 B each (18r x 256)
  __shared__ float redd[8][32];
  __shared__ float dvl[32];

  const _Float16* gA = Wtf + (size_t)byq * 16 * 18432 + hoc * 256;
  // per-wave X fragment base: padded rows h0+2w..h0+2w+3, fragment (kq,n)
  const _Float16* gXw = xsp + (size_t)b * 16 * 36992 +
                        (size_t)(h0 + 2 * w) * 1088 + kq * 272 + n * 8;

  // A chunks c in [0,576): r=c>>5 (0..17), o2=c&31;
  //   src halfs = icb*18432 + kk*1024 + ((r>>1)*4 + (r&1))*512 + o2*8
  // 12 groups of 48 lanes; wave w -> groups 3w..3w+2 (3 g2l/wave, uniform)
  auto stageA = [&](int st, int p) {
    const int icb = st >> 1, kk = st & 1;
    const _Float16* a = gA + (size_t)icb * 18432 + kk * 1024;
    if (lane < 48) {
#pragma unroll
      for (int k = 0; k < 3; ++k) {
        int c = (w * 3 + k) * 48 + lane;
        int r = c >> 5, o2 = c & 31;
        g2l(a + ((r >> 1) * 4 + (r & 1)) * 512 + o2 * 8, &As[p][c * 8]);
      }
    }
  };

  floatx16 acc[2] = {};
  half8 xvA[4][3], xvB[4][3];
  stageA(0, 0);                          // 3 g2l in flight (oldest)
  LOADX(xvA, 0)                          // + 12 X loads
  for (int ii = 0; ii < 32; ii += 2) {
    STEP(ii,     0, xvA, xvB)
    STEP(ii + 1, 1, xvB, xvA)
  }

  // epilogue: reduce dpart over 16 icb -> dvl[32], then plain stores
  const int oc0 = byq * 64 + hoc * 32;
  __syncthreads();
  {
    const int oc_l = tid & 31, ig = tid >> 5;
    float s = dpart[(size_t)(ig * 2) * 4096 + b * OC_ + oc0 + oc_l] +
              dpart[(size_t)(ig * 2 + 1) * 4096 + b * OC_ + oc0 + oc_l];
    redd[ig][oc_l] = s;
  }
  __syncthreads();
  if (tid < 32) {
    float s = 1e-8f;
#pragma unroll
    for (int g = 0; g < 8; ++g) s += redd[g][tid];
    dvl[tid] = rsqrtf(s);
  }
  __syncthreads();
  // D col(px)=n, row(oc within 32)=(rg&3)+8*(rg>>2)+4*kq
  const int r0 = h0 + 2 * w;
#pragma unroll
  for (int rg = 0; rg < 16; ++rg) {
    const int row = (rg & 3) + 8 * (rg >> 2) + 4 * kq;
    const float dv = dvl[row];
    float* op = out + ((size_t)b * OC_ + oc0 + row) * 1024 + r0 * 32 + n;
    op[0]  = acc[0][rg] * dv;
    op[32] = acc[1][rg] * dv;
  }
}

extern "C" void kernel_launch(void* const* d_in, const int* in_sizes, int n_in,
                              void* d_out, int out_size, void* d_ws, size_t ws_size,
                              hipStream_t stream) {
  const float* x       = (const float*)d_in[0];
  const float* w       = (const float*)d_in[1];
  const float* conv_w  = (const float*)d_in[2];
  const float* dense_w = (const float*)d_in[3];
  const float* dense_b = (const float*)d_in[4];
  float* out = (float*)d_out;

  char* ws = (char*)d_ws;
  float*    sm    = (float*)ws;                        // 16 KB
  float*    sm2   = (float*)(ws + (16 << 10));         // 16 KB
  float*    dpart = (float*)(ws + (32 << 10));         // 256 KB
  _Float16* Wtf   = (_Float16*)(ws + (288 << 10));               // 4,718,592 B
  _Float16* xsp   = (_Float16*)(ws + (288 << 10) + 4718592);     // 9,469,952 B

  style_kernel<<<dim3(8, B_), 256, 0, stream>>>(w, dense_w, dense_b, sm, sm2);
  prep_kernel<<<512, 256, 0, stream>>>(conv_w, x, sm, sm2, Wtf, dpart, xsp);
  conv_kernel<<<dim3(16, 4, B_), 256, 0, stream>>>(Wtf, xsp, dpart, out);
}

// Round 11
// 129.303 us; speedup vs baseline: 1.0767x; 1.0767x over previous
//
#include <hip/hip_runtime.h>
#include <stdint.h>

// ModulatedConv2D: B=8, IC=OC=512, K=3, H=W=32
// 3 dispatches: style (sm, sm2), prep (Wtf repack + dpart demod partials +
// xsp repack), conv (implicit GEMM, 32x32x16 f16 MFMA).
//
// R11 change: R10 (X direct->VGPR) regressed (58.7us, MfmaUtil 25%) ->
// reverted; staged-X is right. Nine variants: every staged version is
// 45-48us = 3x the 15.5us MFMA floor, with a CONSTANT ~2300cyc/sub-step
// residual that didn't respond to depth, counted-vmcnt, occupancy, or
// byte-count changes -> hypothesis: fixed per-STEP sync/skew tax paid 32x.
// Test: halve steps (16 x full-icb, 36 MFMA/wave), m201-shaped block:
// 512 thr / 8 waves / 1 block/CU, 64oc x 256px, wave = 32oc x 2rows.
// A (36864B) + X (21760B) identity-linear g2l, dbuf = 117.2KB dynamic LDS
// (hipFuncSetAttribute, HK-style). Exactly 8 g2l/wave -> vmcnt(8).

#define B_   8
#define IC_  512
#define OC_  512

static constexpr float RC_DENSE = 0.04419417382415922f;   // 1/sqrt(512)
static constexpr float RC_CONV  = 0.014731391274719739f;  // 1/sqrt(4608)

typedef _Float16 half8    __attribute__((ext_vector_type(8)));
typedef float    floatx16 __attribute__((ext_vector_type(16)));

// async global->LDS, 16B per lane; LDS dest = wave-uniform base + lane*16
__device__ __forceinline__ void g2l(const void* g, void* l) {
  __builtin_amdgcn_global_load_lds(
      (const __attribute__((address_space(1))) void*)g,
      (__attribute__((address_space(3))) void*)l, 16, 0, 0);
}

// ---- sm = (w@(RC_DENSE*dw) + db + 1)*RC_CONV ; sm2 = sm^2 ----
__global__ __launch_bounds__(256) void style_kernel(
    const float* __restrict__ wv, const float* __restrict__ dw,
    const float* __restrict__ db, float* __restrict__ sm,
    float* __restrict__ sm2) {
  const int b = blockIdx.y;
  const int i = blockIdx.x * 64 + (threadIdx.x & 63);
  const int jg = threadIdx.x >> 6;
  __shared__ float red[4][64];
  float p = 0.f;
  for (int j = jg * 128; j < jg * 128 + 128; ++j)
    p += wv[b * IC_ + j] * dw[(size_t)j * IC_ + i];
  red[jg][threadIdx.x & 63] = p;
  __syncthreads();
  if (threadIdx.x < 64) {
    float s = red[0][threadIdx.x] + red[1][threadIdx.x] +
              red[2][threadIdx.x] + red[3][threadIdx.x];
    s = s * RC_DENSE + db[i] + 1.0f;
    float v = s * RC_CONV;
    sm[b * IC_ + i] = v;
    sm2[b * IC_ + i] = v * v;
  }
}

// ---------------- prep: 512 blocks (2/CU) ----------------
// bid<256 (wts role): 32oc x 32ic half-tile; Wtf[by][icb][ktq 36][oc64][8] f16
//   + dpart[icb][b][oc] = sum_icl sm2 * sum_t cw^2 (disjoint oc, no atomics)
// bid>=256 (xsp role): per (b,h) row; xsp[b][icb][r34][kk2][kq2][C34][8] f16
__global__ __launch_bounds__(256) void prep_kernel(
    const float* __restrict__ cw, const float* __restrict__ x,
    const float* __restrict__ sm, const float* __restrict__ sm2,
    _Float16* __restrict__ Wtf, float* __restrict__ dpart,
    _Float16* __restrict__ xsp) {
  __shared__ __align__(16) char smem[33280];
  const int bid = blockIdx.x;
  const int tid = threadIdx.x;
  if (bid < 256) {
    // ---------------- wts + dpart role ----------------
    _Float16* LA = (_Float16*)smem;                // 18432 B
    float* redall = (float*)(smem + 18432);        // 8192 B (8b x 8g x 32oc)
    const int by2 = bid >> 4, icb = bid & 15;
    const int by = by2 >> 1, h2 = by2 & 1;
    const int oc0 = by * 64 + h2 * 32, ic0 = icb * 32;
    const int ocl = tid & 31, g = tid >> 5;        // g 0..7
    float sq4[4] = {};
    for (int m = 0; m < 36; ++m) {
      int r = m * 8 + g;                 // r = t*32+icl; t=m>>2, icl=8*(m&3)+g
      int t = r >> 5, icl = r & 31;
      float v = cw[(size_t)(t * IC_ + ic0 + icl) * OC_ + oc0 + ocl];  // 128B seg
      sq4[m & 3] += v * v;
      LA[m * 256 + ocl * 8 + g] = (_Float16)v;     // ktq == m, j == g
    }
    for (int b = 0; b < 8; ++b) {
      float p = 0.f;
      for (int s = 0; s < 4; ++s)
        p += sm2[b * IC_ + ic0 + g + 8 * s] * sq4[s];
      redall[(b * 8 + g) * 32 + ocl] = p;
    }
    __syncthreads();
    // Wtf: 1152 contiguous-per-wave b128 chunks
    _Float16* dst = Wtf + (size_t)(by * 16 + icb) * 18432;
    for (int it = 0; it < 5; ++it) {
      int c = it * 256 + tid;
      if (c < 1152) {
        int m = c >> 5, o2 = c & 31;
        *(half8*)(dst + (size_t)(m * 64 + h2 * 32 + o2) * 8) =
            *(const half8*)&LA[m * 256 + o2 * 8];
      }
    }
    // dpart: reduce over g
    const int bb = tid >> 5, o3 = tid & 31;
    float s = 0.f;
    for (int g2 = 0; g2 < 8; ++g2) s += redall[(bb * 8 + g2) * 32 + o3];
    dpart[(size_t)icb * 4096 + bb * OC_ + oc0 + o3] = s;
  } else {
    // ---------------- xsp role ----------------
    _Float16* Xt = (_Float16*)smem;                // 32*520*2 = 33280 B
    const int rb = bid - 256;
    const int b = rb >> 5, h = rb & 31;
    for (int k = 0; k < 16; ++k) {
      int idx = k * 256 + tid;           // 512 ic * 8 w-quads
      int ic = idx >> 3, wc = (idx & 7) * 4;
      float4 v = *(const float4*)&x[((size_t)(b * IC_ + ic) * 32 + h) * 32 + wc];
      float s = sm[b * IC_ + ic];
      Xt[(wc + 0) * 520 + ic] = (_Float16)(v.x * s);
      Xt[(wc + 1) * 520 + ic] = (_Float16)(v.y * s);
      Xt[(wc + 2) * 520 + ic] = (_Float16)(v.z * s);
      Xt[(wc + 3) * 520 + ic] = (_Float16)(v.w * s);
    }
    __syncthreads();
    _Float16* xb = xsp + (size_t)b * 16 * 36992;
    const int r = h + 1;
    half8 z = {};
    for (int it = 0; it < 9; ++it) {     // 16 icb * 4 kkq * 34 C = 2176 chunks
      int c = it * 256 + tid;
      if (c < 2176) {
        int icb = c / 136, rem = c - 136 * icb, kkq = rem / 34, C = rem - 34 * kkq;
        half8 val = z;
        if (C != 0 && C != 33)
          val = *(const half8*)&Xt[(C - 1) * 520 + icb * 32 + kkq * 8];
        *(half8*)&xb[(size_t)icb * 36992 + (size_t)r * 1088 + kkq * 272 + C * 8] = val;
      }
    }
    if (h == 0 || h == 31) {             // zero top/bottom padded rows
      const int rz = (h == 0) ? 0 : 33;
      for (int it = 0; it < 9; ++it) {
        int c = it * 256 + tid;
        if (c < 2176) {
          int icb = c / 136, rem = c - 136 * icb, kkq = rem / 34, C = rem - 34 * kkq;
          *(half8*)&xb[(size_t)icb * 36992 + (size_t)rz * 1088 + kkq * 272 + C * 8] = z;
        }
      }
    }
  }
}

// ---- conv: block 64oc x 256px (8 rows), 512 thr, grid (by 8, bx 4, b 8) ----
// 256 blocks = 1/CU; XCD = linear%8 = by (weight-slice locality).
// 8 waves = wm(2 oc-halves) x wn(4 row-pairs); wave = 32oc x 2 rows,
// acc[2]x16, 36 MFMA per step (full icb: both kk halves).
// 16 steps; per step: A icb tile 36864 B ([36 m][64 oc][8], identity copy)
// + X 10 rows 21760 B ([10 r][2 kk][2 kq][34 C][8], identity copy), both
// via global_load_lds, double-buffered (117.2 KB dynamic LDS).
// Staging: exactly 8 g2l PER WAVE (A: 4 full + 1 @32 lanes = 288 chunks;
// X: 2 full + 1 @42 lanes = 170 chunks) -> counted vmcnt(8), never 0
// in-loop. Two barriers per step (leading RAW, trailing WAR).
__global__ __launch_bounds__(512, 1) void conv_kernel(
    const _Float16* __restrict__ Wtf,   // [8 by][16 icb][36 m][64 oc][8]
    const _Float16* __restrict__ xsp,   // [8 b][16 icb][34 r][2 kk][2 kq][34 C][8]
    const float* __restrict__ dpart,    // [16 icb][8 b][512 oc]
    float* __restrict__ out) {          // [8][512][32][32]
  extern __shared__ __align__(16) _Float16 dyn[];
  _Float16* As0 = dyn;                  // 18432 halfs
  _Float16* As1 = dyn + 18432;
  _Float16* Xs0 = dyn + 36864;          // 10880 halfs
  _Float16* Xs1 = dyn + 47744;
  float* redd = (float*)(dyn + 58624);  // 8*64 floats
  float* dvl  = redd + 512;             // 64 floats

  const int by = blockIdx.x, bx = blockIdx.y, b = blockIdx.z;
  const int tid = threadIdx.x, lane = tid & 63, w = tid >> 6;  // w 0..7
  const int wm = w & 1, wn = w >> 1;    // wm: oc half; wn: row pair
  const int n = lane & 31, kq = lane >> 5;
  const int h0 = bx * 8;                // out rows h0..h0+7; padded h0..h0+9

  const _Float16* gA = Wtf + (size_t)(by * 16) * 18432;
  const _Float16* gX = xsp + (size_t)b * 16 * 36992 + (size_t)h0 * 1088;

  // identity-linear staging; chunk = 16 B. A: 2304 chunks, X: 1360 chunks.
  auto stage = [&](int icb, int p) {
    const _Float16* a  = gA + (size_t)icb * 18432;
    const _Float16* xg = gX + (size_t)icb * 36992;
    _Float16* Ad = p ? As1 : As0;
    _Float16* Xd = p ? Xs1 : Xs0;
#pragma unroll
    for (int k = 0; k < 4; ++k) {        // A full groups
      int c = w * 288 + k * 64 + lane;
      g2l(a + (size_t)c * 8, Ad + c * 8);
    }
    {                                    // A partial (32 lanes)
      int c = w * 288 + 256 + lane;
      if (lane < 32) g2l(a + (size_t)c * 8, Ad + c * 8);
    }
#pragma unroll
    for (int k = 0; k < 2; ++k) {        // X full groups
      int c = w * 170 + k * 64 + lane;
      g2l(xg + (size_t)c * 8, Xd + c * 8);
    }
    {                                    // X partial (42 lanes)
      int c = w * 170 + 128 + lane;
      if (lane < 42) g2l(xg + (size_t)c * 8, Xd + c * 8);
    }
  };

  floatx16 acc[2] = {};
  stage(0, 0);                           // 8 g2l in flight
  for (int st = 0; st < 16; ++st) {
    const int cur = st & 1;
    if (st + 1 < 16) {
      stage(st + 1, cur ^ 1);            // +8 -> 16 in flight
      __builtin_amdgcn_sched_barrier(0);
      asm volatile("s_waitcnt vmcnt(8)" ::: "memory");   // stage(st) done
    } else {
      __builtin_amdgcn_sched_barrier(0);
      asm volatile("s_waitcnt vmcnt(0)" ::: "memory");
    }
    __builtin_amdgcn_s_barrier();        // buf[cur] visible to all waves
    __builtin_amdgcn_sched_barrier(0);
    // A frag (t,kk): [m = t*4 + kk*2 + kq][wm*32 + n] -> 9x2 ds_read_b128
    const _Float16* Ar = (cur ? As1 : As0) + kq * 512 + wm * 256 + n * 8;
    const _Float16* Xr = (cur ? Xs1 : Xs0) + (2 * wn) * 1088 + kq * 272 + n * 8;
    half8 a[9][2];
#pragma unroll
    for (int t = 0; t < 9; ++t) {
      a[t][0] = *(const half8*)(Ar + (t * 4 + 0) * 512);
      a[t][1] = *(const half8*)(Ar + (t * 4 + 2) * 512);
    }
    __builtin_amdgcn_s_setprio(1);
#pragma unroll
    for (int kk = 0; kk < 2; ++kk) {
#pragma unroll
      for (int s = 0; s < 4; ++s) {      // staged row 2wn+s; out rows j=0,1
#pragma unroll
        for (int kw = 0; kw < 3; ++kw) {
          half8 xv = *(const half8*)(Xr + s * 1088 + kk * 544 + kw * 8);
#pragma unroll
          for (int kh = 0; kh < 3; ++kh) {
            int j = s - kh;
            if (j >= 0 && j < 2)
              acc[j] = __builtin_amdgcn_mfma_f32_32x32x16_f16(
                  a[kh * 3 + kw][kk], xv, acc[j], 0, 0, 0);
          }
        }
      }
    }
    __builtin_amdgcn_s_setprio(0);
    __builtin_amdgcn_sched_barrier(0);
    __builtin_amdgcn_s_barrier();        // buf[cur^1] reads done (WAR)
  }

  // epilogue: reduce dpart over 16 icb -> dvl[64], then plain stores
  const int oc0 = by * 64 + wm * 32;
  __syncthreads();
  {
    const int oc_l = tid & 63, ig = tid >> 6;   // 8 groups x 64 oc
    float s = dpart[(size_t)(ig * 2) * 4096 + b * OC_ + by * 64 + oc_l] +
              dpart[(size_t)(ig * 2 + 1) * 4096 + b * OC_ + by * 64 + oc_l];
    redd[ig * 64 + oc_l] = s;
  }
  __syncthreads();
  if (tid < 64) {
    float s = 1e-8f;
#pragma unroll
    for (int g = 0; g < 8; ++g) s += redd[g * 64 + tid];
    dvl[tid] = rsqrtf(s);
  }
  __syncthreads();
  // D col(px)=n, row(oc within 32)=(rg&3)+8*(rg>>2)+4*kq
  const int r0 = h0 + 2 * wn;
#pragma unroll
  for (int rg = 0; rg < 16; ++rg) {
    const int row = (rg & 3) + 8 * (rg >> 2) + 4 * kq;
    const float dv = dvl[wm * 32 + row];
    float* op = out + ((size_t)b * OC_ + oc0 + row) * 1024 + r0 * 32 + n;
    op[0]  = acc[0][rg] * dv;
    op[32] = acc[1][rg] * dv;
  }
}

extern "C" void kernel_launch(void* const* d_in, const int* in_sizes, int n_in,
                              void* d_out, int out_size, void* d_ws, size_t ws_size,
                              hipStream_t stream) {
  const float* x       = (const float*)d_in[0];
  const float* w       = (const float*)d_in[1];
  const float* conv_w  = (const float*)d_in[2];
  const float* dense_w = (const float*)d_in[3];
  const float* dense_b = (const float*)d_in[4];
  float* out = (float*)d_out;

  char* ws = (char*)d_ws;
  float*    sm    = (float*)ws;                        // 16 KB
  float*    sm2   = (float*)(ws + (16 << 10));         // 16 KB
  float*    dpart = (float*)(ws + (32 << 10));         // 256 KB
  _Float16* Wtf   = (_Float16*)(ws + (288 << 10));               // 4,718,592 B
  _Float16* xsp   = (_Float16*)(ws + (288 << 10) + 4718592);     // 9,469,952 B

  static int dyn_set = 0;
  if (!dyn_set) {
    hipFuncSetAttribute((const void*)conv_kernel,
                        hipFuncAttributeMaxDynamicSharedMemorySize, 119552);
    dyn_set = 1;
  }

  style_kernel<<<dim3(8, B_), 256, 0, stream>>>(w, dense_w, dense_b, sm, sm2);
  prep_kernel<<<512, 256, 0, stream>>>(conv_w, x, sm, sm2, Wtf, dpart, xsp);
  conv_kernel<<<dim3(8, 4, B_), 512, 119552, stream>>>(Wtf, xsp, dpart, out);
}

// Round 12
// 125.629 us; speedup vs baseline: 1.1082x; 1.0292x over previous
//
#include <hip/hip_runtime.h>
#include <stdint.h>

// ModulatedConv2D: B=8, IC=OC=512, K=3, H=W=32
// 3 dispatches: style (sm, sm2), prep (Wtf repack + dpart demod partials +
// xsp repack), conv (implicit GEMM, 32x32x16 f16 MFMA).
//
// R12 change: ten conv variants pinned at 45-48us / MfmaUtil 33% -- ALL were
// the coarse 2-phase schedule (m233's measured ~3x stall; counted-vmcnt and
// setprio are null in that regime per the T-catalog regime gate). This round
// ports the m201 8-PHASE schedule (the +28-41% lever, m196/m198): each step
// = 4 phases {ds_reads ; 2-3 g2l of a half-tile 3-AHEAD ; s_barrier ;
// lgkmcnt(0)+sched_barrier(0) ; setprio(1) 9 MFMA setprio(0) ; vmcnt(10)
// at phases 2/4 only ; s_barrier}. Staging = kk-half granularity, 5 g2l
// per wave per half (3 A + 2 X, uniform), 4 region-buffers x 2 parities
// (same 119.5 KB dynamic LDS as R11), prologue = 3 halves. Per-wave vmcnt
// verified: 10/10 steady, (10,5) and (0,-) in peeled tail steps.

#define B_   8
#define IC_  512
#define OC_  512

static constexpr float RC_DENSE = 0.04419417382415922f;   // 1/sqrt(512)
static constexpr float RC_CONV  = 0.014731391274719739f;  // 1/sqrt(4608)

typedef _Float16 half8    __attribute__((ext_vector_type(8)));
typedef float    floatx16 __attribute__((ext_vector_type(16)));

// async global->LDS, 16B per lane; LDS dest = wave-uniform base + lane*16
__device__ __forceinline__ void g2l(const void* g, void* l) {
  __builtin_amdgcn_global_load_lds(
      (const __attribute__((address_space(1))) void*)g,
      (__attribute__((address_space(3))) void*)l, 16, 0, 0);
}

// ---- sm = (w@(RC_DENSE*dw) + db + 1)*RC_CONV ; sm2 = sm^2 ----
__global__ __launch_bounds__(256) void style_kernel(
    const float* __restrict__ wv, const float* __restrict__ dw,
    const float* __restrict__ db, float* __restrict__ sm,
    float* __restrict__ sm2) {
  const int b = blockIdx.y;
  const int i = blockIdx.x * 64 + (threadIdx.x & 63);
  const int jg = threadIdx.x >> 6;
  __shared__ float red[4][64];
  float p = 0.f;
  for (int j = jg * 128; j < jg * 128 + 128; ++j)
    p += wv[b * IC_ + j] * dw[(size_t)j * IC_ + i];
  red[jg][threadIdx.x & 63] = p;
  __syncthreads();
  if (threadIdx.x < 64) {
    float s = red[0][threadIdx.x] + red[1][threadIdx.x] +
              red[2][threadIdx.x] + red[3][threadIdx.x];
    s = s * RC_DENSE + db[i] + 1.0f;
    float v = s * RC_CONV;
    sm[b * IC_ + i] = v;
    sm2[b * IC_ + i] = v * v;
  }
}

// ---------------- prep: 512 blocks (2/CU) ----------------
// bid<256 (wts role): 32oc x 32ic half-tile; Wtf[by][icb][ktq 36][oc64][8] f16
//   + dpart[icb][b][oc] = sum_icl sm2 * sum_t cw^2 (disjoint oc, no atomics)
// bid>=256 (xsp role): per (b,h) row; xsp[b][icb][r34][kk2][kq2][C34][8] f16
__global__ __launch_bounds__(256) void prep_kernel(
    const float* __restrict__ cw, const float* __restrict__ x,
    const float* __restrict__ sm, const float* __restrict__ sm2,
    _Float16* __restrict__ Wtf, float* __restrict__ dpart,
    _Float16* __restrict__ xsp) {
  __shared__ __align__(16) char smem[33280];
  const int bid = blockIdx.x;
  const int tid = threadIdx.x;
  if (bid < 256) {
    // ---------------- wts + dpart role ----------------
    _Float16* LA = (_Float16*)smem;                // 18432 B
    float* redall = (float*)(smem + 18432);        // 8192 B (8b x 8g x 32oc)
    const int by2 = bid >> 4, icb = bid & 15;
    const int by = by2 >> 1, h2 = by2 & 1;
    const int oc0 = by * 64 + h2 * 32, ic0 = icb * 32;
    const int ocl = tid & 31, g = tid >> 5;        // g 0..7
    float sq4[4] = {};
    for (int m = 0; m < 36; ++m) {
      int r = m * 8 + g;                 // r = t*32+icl; t=m>>2, icl=8*(m&3)+g
      int t = r >> 5, icl = r & 31;
      float v = cw[(size_t)(t * IC_ + ic0 + icl) * OC_ + oc0 + ocl];  // 128B seg
      sq4[m & 3] += v * v;
      LA[m * 256 + ocl * 8 + g] = (_Float16)v;     // ktq == m, j == g
    }
    for (int b = 0; b < 8; ++b) {
      float p = 0.f;
      for (int s = 0; s < 4; ++s)
        p += sm2[b * IC_ + ic0 + g + 8 * s] * sq4[s];
      redall[(b * 8 + g) * 32 + ocl] = p;
    }
    __syncthreads();
    // Wtf: 1152 contiguous-per-wave b128 chunks
    _Float16* dst = Wtf + (size_t)(by * 16 + icb) * 18432;
    for (int it = 0; it < 5; ++it) {
      int c = it * 256 + tid;
      if (c < 1152) {
        int m = c >> 5, o2 = c & 31;
        *(half8*)(dst + (size_t)(m * 64 + h2 * 32 + o2) * 8) =
            *(const half8*)&LA[m * 256 + o2 * 8];
      }
    }
    // dpart: reduce over g
    const int bb = tid >> 5, o3 = tid & 31;
    float s = 0.f;
    for (int g2 = 0; g2 < 8; ++g2) s += redall[(bb * 8 + g2) * 32 + o3];
    dpart[(size_t)icb * 4096 + bb * OC_ + oc0 + o3] = s;
  } else {
    // ---------------- xsp role ----------------
    _Float16* Xt = (_Float16*)smem;                // 32*520*2 = 33280 B
    const int rb = bid - 256;
    const int b = rb >> 5, h = rb & 31;
    for (int k = 0; k < 16; ++k) {
      int idx = k * 256 + tid;           // 512 ic * 8 w-quads
      int ic = idx >> 3, wc = (idx & 7) * 4;
      float4 v = *(const float4*)&x[((size_t)(b * IC_ + ic) * 32 + h) * 32 + wc];
      float s = sm[b * IC_ + ic];
      Xt[(wc + 0) * 520 + ic] = (_Float16)(v.x * s);
      Xt[(wc + 1) * 520 + ic] = (_Float16)(v.y * s);
      Xt[(wc + 2) * 520 + ic] = (_Float16)(v.z * s);
      Xt[(wc + 3) * 520 + ic] = (_Float16)(v.w * s);
    }
    __syncthreads();
    _Float16* xb = xsp + (size_t)b * 16 * 36992;
    const int r = h + 1;
    half8 z = {};
    for (int it = 0; it < 9; ++it) {     // 16 icb * 4 kkq * 34 C = 2176 chunks
      int c = it * 256 + tid;
      if (c < 2176) {
        int icb = c / 136, rem = c - 136 * icb, kkq = rem / 34, C = rem - 34 * kkq;
        half8 val = z;
        if (C != 0 && C != 33)
          val = *(const half8*)&Xt[(C - 1) * 520 + icb * 32 + kkq * 8];
        *(half8*)&xb[(size_t)icb * 36992 + (size_t)r * 1088 + kkq * 272 + C * 8] = val;
      }
    }
    if (h == 0 || h == 31) {             // zero top/bottom padded rows
      const int rz = (h == 0) ? 0 : 33;
      for (int it = 0; it < 9; ++it) {
        int c = it * 256 + tid;
        if (c < 2176) {
          int icb = c / 136, rem = c - 136 * icb, kkq = rem / 34, C = rem - 34 * kkq;
          *(half8*)&xb[(size_t)icb * 36992 + (size_t)rz * 1088 + kkq * 272 + C * 8] = z;
        }
      }
    }
  }
}

// ---- conv: block 64oc x 256px (8 rows), 512 thr, grid (by 8, bx 4, b 8) ----
// 256 blocks = 1/CU; XCD = linear%8 = by (weight-slice locality).
// 8 waves = wm(2 oc-halves) x wn(4 row-pairs); wave = 32oc x 2 rows,
// acc[2]x16, 36 MFMA per step, 16 steps (full icb each).
// 8-phase-style schedule: 4 phases per step; half-tile (kk-half of an icb:
// A 9216B + X 5440B) staged 3 halves ahead; 5 g2l/wave/half (3 A + 2 X).
// LDS: A regions [kk][par][9216 halfs] + X regions [kk][par][5440 halfs],
// parity = icb&1. vmcnt(10) at phases 2/4 only (never 0 in main loop).

#define VM10 asm volatile("s_waitcnt vmcnt(10)" ::: "memory")
#define VM5  asm volatile("s_waitcnt vmcnt(5)" ::: "memory")
#define VM0  asm volatile("s_waitcnt vmcnt(0)" ::: "memory")
#define VMNONE ((void)0)

// one phase: ds_reads -> g2l -> bar -> lgkm0 -> 9 MFMA -> [vmcnt] -> bar
#define PHASE(KK, SH, PAR, DO_A, G2L_STMT, VM_STMT)                          \
  {                                                                          \
    if (DO_A) {                                                              \
      const _Float16* Ad = dyn + ((KK) * 2 + (PAR)) * 9216 +                 \
                           kq * 512 + wm * 256 + n * 8;                      \
      _Pragma("unroll")                                                      \
      for (int t_ = 0; t_ < 9; ++t_)                                         \
        av[t_] = *(const half8*)(Ad + (t_ * 2) * 512);                       \
    }                                                                        \
    const _Float16* Xd = XB + ((KK) * 2 + (PAR)) * 5440 +                    \
                         (2 * wn + 2 * (SH)) * 544 + kq * 272 + n * 8;       \
    half8 xv0[3], xv1[3];                                                    \
    _Pragma("unroll")                                                        \
    for (int kw_ = 0; kw_ < 3; ++kw_) {                                      \
      xv0[kw_] = *(const half8*)(Xd + kw_ * 8);                              \
      xv1[kw_] = *(const half8*)(Xd + 544 + kw_ * 8);                        \
    }                                                                        \
    G2L_STMT;                                                                \
    __builtin_amdgcn_s_barrier();                                            \
    asm volatile("s_waitcnt lgkmcnt(0)" ::: "memory");                       \
    __builtin_amdgcn_sched_barrier(0);                                       \
    __builtin_amdgcn_s_setprio(1);                                           \
    _Pragma("unroll")                                                        \
    for (int kw_ = 0; kw_ < 3; ++kw_) {                                      \
      if (SH == 0) {                                                         \
        acc[0] = __builtin_amdgcn_mfma_f32_32x32x16_f16(av[0 + kw_], xv0[kw_], acc[0], 0, 0, 0); \
        acc[1] = __builtin_amdgcn_mfma_f32_32x32x16_f16(av[0 + kw_], xv1[kw_], acc[1], 0, 0, 0); \
        acc[0] = __builtin_amdgcn_mfma_f32_32x32x16_f16(av[3 + kw_], xv1[kw_], acc[0], 0, 0, 0); \
      } else {                                                               \
        acc[1] = __builtin_amdgcn_mfma_f32_32x32x16_f16(av[3 + kw_], xv0[kw_], acc[1], 0, 0, 0); \
        acc[0] = __builtin_amdgcn_mfma_f32_32x32x16_f16(av[6 + kw_], xv0[kw_], acc[0], 0, 0, 0); \
        acc[1] = __builtin_amdgcn_mfma_f32_32x32x16_f16(av[6 + kw_], xv1[kw_], acc[1], 0, 0, 0); \
      }                                                                      \
    }                                                                        \
    __builtin_amdgcn_s_setprio(0);                                           \
    __builtin_amdgcn_sched_barrier(0);                                       \
    VM_STMT;                                                                 \
    __builtin_amdgcn_s_barrier();                                            \
  }

__global__ __launch_bounds__(512, 1) void conv_kernel(
    const _Float16* __restrict__ Wtf,   // [8 by][16 icb][36 m][64 oc][8]
    const _Float16* __restrict__ xsp,   // [8 b][16 icb][34 r][2 kk][2 kq][34 C][8]
    const float* __restrict__ dpart,    // [16 icb][8 b][512 oc]
    float* __restrict__ out) {          // [8][512][32][32]
  extern __shared__ __align__(16) _Float16 dyn[];
  _Float16* XB = dyn + 36864;           // X regions base (halfs)
  float* redd = (float*)(dyn + 58624);  // 8*64 floats
  float* dvl  = redd + 512;             // 64 floats

  const int by = blockIdx.x, bx = blockIdx.y, b = blockIdx.z;
  const int tid = threadIdx.x, lane = tid & 63, w = tid >> 6;  // w 0..7
  const int wm = w & 1, wn = w >> 1;    // wm: oc half; wn: row pair
  const int n = lane & 31, kq = lane >> 5;
  const int h0 = bx * 8;                // out rows h0..h0+7; padded h0..h0+9

  const _Float16* gA = Wtf + (size_t)(by * 16) * 18432;
  const _Float16* gX = xsp + (size_t)b * 16 * 36992 + (size_t)h0 * 1088;

  // A-half(kk) of icb: 18 m-values (m = (mi>>1)*4 + kk*2 + (mi&1)),
  // 1152 chunks; wave w covers c in [w*144, w*144+144): 2 full + 1@16.
  auto stageA3 = [&](int g) {
    const int icb = g >> 1, kk = g & 1, par = icb & 1;
    const _Float16* a = gA + (size_t)icb * 18432;
    _Float16* Ad = dyn + (kk * 2 + par) * 9216;
#pragma unroll
    for (int k = 0; k < 2; ++k) {
      int c = w * 144 + k * 64 + lane;
      int mi = c >> 6, o = c & 63;
      int m = (mi >> 1) * 4 + kk * 2 + (mi & 1);
      g2l(a + (size_t)(m * 512 + o * 8), Ad + c * 8);
    }
    {
      int c = w * 144 + 128 + lane;
      if (lane < 16) {
        int mi = c >> 6, o = c & 63;
        int m = (mi >> 1) * 4 + kk * 2 + (mi & 1);
        g2l(a + (size_t)(m * 512 + o * 8), Ad + c * 8);
      }
    }
  };
  // X-half(kk) of icb: 10 rows x 544 halfs = 680 chunks; wave w covers
  // c in [w*85, w*85+85): 1 full + 1@21.
  auto stageX2 = [&](int g) {
    const int icb = g >> 1, kk = g & 1, par = icb & 1;
    const _Float16* xg = gX + (size_t)icb * 36992 + kk * 544;
    _Float16* Xd = XB + (kk * 2 + par) * 5440;
    {
      int c = w * 85 + lane;
      int r = c / 68, o = c - r * 68;
      g2l(xg + (size_t)(r * 1088 + o * 8), Xd + c * 8);
    }
    {
      int c = w * 85 + 64 + lane;
      if (lane < 21) {
        int r = c / 68, o = c - r * 68;
        g2l(xg + (size_t)(r * 1088 + o * 8), Xd + c * 8);
      }
    }
  };

  floatx16 acc[2] = {};
  half8 av[9];
  // prologue: stage halves 0,1,2 (15 g2l/wave); drain half0; barrier.
  stageA3(0); stageX2(0);
  stageA3(1); stageX2(1);
  stageA3(2); stageX2(2);
  VM10;                                  // <=10 left: halves 1,2
  __builtin_amdgcn_s_barrier();

  for (int st = 0; st < 14; ++st) {
    const int par = st & 1;
    const int g3 = 2 * st + 3, g4 = 2 * st + 4;
    PHASE(0, 0, par, true,  stageA3(g3), VMNONE)
    PHASE(0, 1, par, false, stageX2(g3), VM10)   // drains half 2st+1 for P3
    PHASE(1, 0, par, true,  stageA3(g4), VMNONE)
    PHASE(1, 1, par, false, stageX2(g4), VM10)   // drains half 2st+2 for next P1
  }
  // st = 14 (par 0): stage half 31 only
  PHASE(0, 0, 0, true,  stageA3(31), VMNONE)
  PHASE(0, 1, 0, false, stageX2(31), VM10)       // drains half 29
  PHASE(1, 0, 0, true,  VMNONE, VMNONE)
  PHASE(1, 1, 0, false, VMNONE, VM5)             // drains half 30
  // st = 15 (par 1): no staging
  PHASE(0, 0, 1, true,  VMNONE, VMNONE)
  PHASE(0, 1, 1, false, VMNONE, VM0)             // drains half 31
  PHASE(1, 0, 1, true,  VMNONE, VMNONE)
  PHASE(1, 1, 1, false, VMNONE, VMNONE)

  // epilogue: reduce dpart over 16 icb -> dvl[64], then plain stores
  const int oc0 = by * 64 + wm * 32;
  __syncthreads();
  {
    const int oc_l = tid & 63, ig = tid >> 6;   // 8 groups x 64 oc
    float s = dpart[(size_t)(ig * 2) * 4096 + b * OC_ + by * 64 + oc_l] +
              dpart[(size_t)(ig * 2 + 1) * 4096 + b * OC_ + by * 64 + oc_l];
    redd[ig * 64 + oc_l] = s;
  }
  __syncthreads();
  if (tid < 64) {
    float s = 1e-8f;
#pragma unroll
    for (int g = 0; g < 8; ++g) s += redd[g * 64 + tid];
    dvl[tid] = rsqrtf(s);
  }
  __syncthreads();
  // D col(px)=n, row(oc within 32)=(rg&3)+8*(rg>>2)+4*kq
  const int r0 = h0 + 2 * wn;
#pragma unroll
  for (int rg = 0; rg < 16; ++rg) {
    const int row = (rg & 3) + 8 * (rg >> 2) + 4 * kq;
    const float dv = dvl[wm * 32 + row];
    float* op = out + ((size_t)b * OC_ + oc0 + row) * 1024 + r0 * 32 + n;
    op[0]  = acc[0][rg] * dv;
    op[32] = acc[1][rg] * dv;
  }
}

extern "C" void kernel_launch(void* const* d_in, const int* in_sizes, int n_in,
                              void* d_out, int out_size, void* d_ws, size_t ws_size,
                              hipStream_t stream) {
  const float* x       = (const float*)d_in[0];
  const float* w       = (const float*)d_in[1];
  const float* conv_w  = (const float*)d_in[2];
  const float* dense_w = (const float*)d_in[3];
  const float* dense_b = (const float*)d_in[4];
  float* out = (float*)d_out;

  char* ws = (char*)d_ws;
  float*    sm    = (float*)ws;                        // 16 KB
  float*    sm2   = (float*)(ws + (16 << 10));         // 16 KB
  float*    dpart = (float*)(ws + (32 << 10));         // 256 KB
  _Float16* Wtf   = (_Float16*)(ws + (288 << 10));               // 4,718,592 B
  _Float16* xsp   = (_Float16*)(ws + (288 << 10) + 4718592);     // 9,469,952 B

  static int dyn_set = 0;
  if (!dyn_set) {
    hipFuncSetAttribute((const void*)conv_kernel,
                        hipFuncAttributeMaxDynamicSharedMemorySize, 119552);
    dyn_set = 1;
  }

  style_kernel<<<dim3(8, B_), 256, 0, stream>>>(w, dense_w, dense_b, sm, sm2);
  prep_kernel<<<512, 256, 0, stream>>>(conv_w, x, sm, sm2, Wtf, dpart, xsp);
  conv_kernel<<<dim3(8, 4, B_), 512, 119552, stream>>>(Wtf, xsp, dpart, out);
}